// Round 1
// baseline (75.106 us; speedup 1.0000x reference)
//
#include <hip/hip_runtime.h>

// QuantumClassifier: 4-qubit, 1-layer circuit, batched over B = 2,097,152.
//
// Closed form (derived from the reference):
//   - After RY(x_i) then Rot(phi,theta,omega) the state is a product state.
//   - CNOT ring (0,1),(1,2),(2,3),(3,0) permutes basis states; final wire-0
//     bit = i1^i2^i3, so <Z0> = (p0[0]+p0[1]) * prod_{k=1..3}(pk[0]-pk[1]).
//   - Per qubit: pk[0]-pk[1] = cos(theta_k)cos(x_k) - cos(phi_k)sin(theta_k)sin(x_k);
//     omega_k drops out; qubit-0 norm == 1.
//   => out[b] = z1*z2*z3  (x[b,0] is irrelevant).
//
// Memory-bound elementwise kernel: float4 load per thread, 1 float store.

#define BLOCK 256

__global__ __launch_bounds__(BLOCK) void qc_kernel(
    const float4* __restrict__ x,   // [B] of float4 = x[b, 0..3]
    const float* __restrict__ w,    // [1,4,3] flat: qubit k -> (phi,theta,omega) at w[3k+..]
    float* __restrict__ out,        // [B]
    int nb)
{
    int b = blockIdx.x * BLOCK + threadIdx.x;
    if (b >= nb) return;

    // Wave-uniform constants from weights (cached/broadcast loads; recomputed
    // per thread to avoid a second kernel launch in the graph).
    float A1 = __cosf(w[4]);
    float B1 = __cosf(w[3]) * __sinf(w[4]);
    float A2 = __cosf(w[7]);
    float B2 = __cosf(w[6]) * __sinf(w[7]);
    float A3 = __cosf(w[10]);
    float B3 = __cosf(w[9]) * __sinf(w[10]);

    float4 v = x[b];  // coalesced 16 B/lane

    float s1 = __sinf(v.y), c1 = __cosf(v.y);
    float s2 = __sinf(v.z), c2 = __cosf(v.z);
    float s3 = __sinf(v.w), c3 = __cosf(v.w);

    float z1 = A1 * c1 - B1 * s1;
    float z2 = A2 * c2 - B2 * s2;
    float z3 = A3 * c3 - B3 * s3;

    out[b] = z1 * z2 * z3;
}

extern "C" void kernel_launch(void* const* d_in, const int* in_sizes, int n_in,
                              void* d_out, int out_size, void* d_ws, size_t ws_size,
                              hipStream_t stream) {
    const float4* x = (const float4*)d_in[0];   // [B,4] float32
    const float*  w = (const float*)d_in[1];    // [1,4,3] float32
    float* out = (float*)d_out;                 // [B] float32

    int nb = in_sizes[0] / 4;                   // batch size
    int grid = (nb + BLOCK - 1) / BLOCK;
    qc_kernel<<<grid, BLOCK, 0, stream>>>(x, w, out, nb);
}

// Round 2
// 74.688 us; speedup vs baseline: 1.0056x; 1.0056x over previous
//
#include <hip/hip_runtime.h>

// QuantumClassifier: 4-qubit, 1-layer circuit, batched over B = 2,097,152.
//
// Closed form (verified R0, absmax 3.9e-3 vs 2e-2 threshold):
//   out[b] = z1*z2*z3,  zk = cos(theta_k)cos(x_k) - cos(phi_k)sin(theta_k)sin(x_k)
//   (omega drops out; qubit 0 contributes exactly 1; x[b,0] irrelevant).
//
// Memory-bound elementwise: floor = 32 MB read + 8 MB write ~ 6.4 us @ 6.3 TB/s.
// R1: 4 elements/thread, split into 4 contiguous chunks so every load/store
// instruction stays perfectly coalesced; 4 independent dependency chains
// hide HBM latency with 1/4 the waves.

#define BLOCK 256
#define VPT 4  // elements per thread

__global__ __launch_bounds__(BLOCK) void qc_kernel(
    const float4* __restrict__ x,   // [B] of float4 = x[b, 0..3]
    const float* __restrict__ w,    // [1,4,3] flat: qubit k -> (phi,theta,omega)
    float* __restrict__ out,        // [B]
    int quarter)                    // B / 4
{
    int i = blockIdx.x * BLOCK + threadIdx.x;
    if (i >= quarter) return;

    // Wave-uniform weight-derived constants (L2-resident, broadcast).
    float A1 = __cosf(w[4]);
    float B1 = __cosf(w[3]) * __sinf(w[4]);
    float A2 = __cosf(w[7]);
    float B2 = __cosf(w[6]) * __sinf(w[7]);
    float A3 = __cosf(w[10]);
    float B3 = __cosf(w[9]) * __sinf(w[10]);

    float4 v0 = x[i];
    float4 v1 = x[i + quarter];
    float4 v2 = x[i + 2 * quarter];
    float4 v3 = x[i + 3 * quarter];

    #pragma unroll
    for (int u = 0; u < VPT; ++u) {
        float4 v = (u == 0) ? v0 : (u == 1) ? v1 : (u == 2) ? v2 : v3;
        float z1 = A1 * __cosf(v.y) - B1 * __sinf(v.y);
        float z2 = A2 * __cosf(v.z) - B2 * __sinf(v.z);
        float z3 = A3 * __cosf(v.w) - B3 * __sinf(v.w);
        out[i + u * quarter] = z1 * z2 * z3;
    }
}

extern "C" void kernel_launch(void* const* d_in, const int* in_sizes, int n_in,
                              void* d_out, int out_size, void* d_ws, size_t ws_size,
                              hipStream_t stream) {
    const float4* x = (const float4*)d_in[0];   // [B,4] float32
    const float*  w = (const float*)d_in[1];    // [1,4,3] float32
    float* out = (float*)d_out;                 // [B] float32

    int nb = in_sizes[0] / 4;                   // batch size (2,097,152)
    int quarter = nb / 4;
    int grid = (quarter + BLOCK - 1) / BLOCK;
    qc_kernel<<<grid, BLOCK, 0, stream>>>(x, w, out, quarter);
}